// Round 1
// baseline (1835.602 us; speedup 1.0000x reference)
//
#include <hip/hip_runtime.h>
#include <cmath>

#define T_SEQ 2048
#define NH    16
#define HD    64
#define DM    1024
#define BATCH 4

// -------------------------------------------------------------------------
// Kernel 1: mask prep. padding_mask: True(=1) = pad. If an entire row is
// padded, unmask it (safe softmax). Writes valid[b][t] in {0,1} as float.
// -------------------------------------------------------------------------
__global__ void maskprep_kernel(const int* __restrict__ pad, float* __restrict__ valid)
{
    __shared__ int sall[256];
    const int b = blockIdx.x;
    const int t = threadIdx.x;
    int allp = 1;
    for (int i = t; i < T_SEQ; i += 256) allp &= (pad[b*T_SEQ + i] != 0) ? 1 : 0;
    sall[t] = allp;
    __syncthreads();
    for (int s = 128; s > 0; s >>= 1) {
        if (t < s) sall[t] &= sall[t + s];
        __syncthreads();
    }
    const int ap = sall[0];
    for (int i = t; i < T_SEQ; i += 256) {
        const int p = (pad[b*T_SEQ + i] != 0) ? 1 : 0;
        valid[b*T_SEQ + i] = (p && !ap) ? 0.0f : 1.0f;
    }
}

// -------------------------------------------------------------------------
// Kernel 2/4: fp32 SGEMM, C[M,N] = A[M,K]@B[K,N] + bias.
// 128x128 block tile, BK=16, 256 threads, 8x8 micro-tile per thread in a
// split 4+4 row/col pattern (keeps LDS reads 2-way-aliased = free, and the
// 4-wide col groups even-aligned for the RoPE pair epilogue).
// EPI=0: plain store to O0 (row-major [M,N]).
// EPI=1: QKV epilogue: bias + RoPE on q/k, scatter to O0/O1/O2 = Q/K/V
//        laid out [B*H][T][64].
// -------------------------------------------------------------------------
template<int EPI>
__global__ __launch_bounds__(256, 2)
void sgemm_kernel(const float* __restrict__ A, const float* __restrict__ B,
                  const float* __restrict__ bias,
                  float* __restrict__ O0, float* __restrict__ O1, float* __restrict__ O2,
                  int M, int N, int K)
{
    __shared__ float As[16][132];   // A-tile transposed: As[k][m], pad to 132
    __shared__ float Bs[16][132];   // B-tile natural:    Bs[k][n]
    const int tid = threadIdx.x;
    const int tx  = tid & 15;
    const int ty  = tid >> 4;
    const int m0  = blockIdx.y * 128;
    const int n0  = blockIdx.x * 128;

    float acc[8][8];
#pragma unroll
    for (int i = 0; i < 8; ++i)
#pragma unroll
        for (int j = 0; j < 8; ++j) acc[i][j] = 0.0f;

    for (int kk = 0; kk < K; kk += 16) {
        __syncthreads();
        // A: 128 rows x 16 k  (float4 along k, scatter-store transposed)
#pragma unroll
        for (int p = 0; p < 2; ++p) {
            const int idx = tid + p * 256;          // 0..511
            const int m   = idx >> 2;               // 0..127
            const int kg  = (idx & 3) * 4;          // 0,4,8,12
            const float4 a = *(const float4*)&A[(size_t)(m0 + m) * K + kk + kg];
            As[kg+0][m] = a.x; As[kg+1][m] = a.y; As[kg+2][m] = a.z; As[kg+3][m] = a.w;
        }
        // B: 16 k x 128 n (float4 along n, natural layout)
#pragma unroll
        for (int p = 0; p < 2; ++p) {
            const int idx = tid + p * 256;
            const int kr  = idx >> 5;               // 0..15
            const int c   = (idx & 31) * 4;         // 0..124
            *(float4*)&Bs[kr][c] = *(const float4*)&B[(size_t)(kk + kr) * N + n0 + c];
        }
        __syncthreads();
#pragma unroll
        for (int k = 0; k < 16; ++k) {
            float a[8], b[8];
            *(float4*)&a[0] = *(const float4*)&As[k][ty*4];
            *(float4*)&a[4] = *(const float4*)&As[k][64 + ty*4];
            *(float4*)&b[0] = *(const float4*)&Bs[k][tx*4];
            *(float4*)&b[4] = *(const float4*)&Bs[k][64 + tx*4];
#pragma unroll
            for (int i = 0; i < 8; ++i)
#pragma unroll
                for (int j = 0; j < 8; ++j)
                    acc[i][j] = fmaf(a[i], b[j], acc[i][j]);
        }
    }

    // ---------------- epilogue ----------------
#pragma unroll
    for (int i = 0; i < 8; ++i) {
        const int m = m0 + ((i < 4) ? (ty*4 + i) : (64 + ty*4 + i - 4));
#pragma unroll
        for (int g = 0; g < 2; ++g) {
            const int n = n0 + g*64 + tx*4;
            float v[4];
#pragma unroll
            for (int j = 0; j < 4; ++j) v[j] = acc[i][g*4 + j] + bias[n + j];
            if (EPI == 0) {
                *(float4*)&O0[(size_t)m * N + n] = make_float4(v[0], v[1], v[2], v[3]);
            } else {
                const int b     = m >> 11;          // /2048
                const int t     = m & 2047;
                const int which = n >> 10;          // 0=q 1=k 2=v
                const int w     = n & 1023;
                const int h     = w >> 6;
                const int d     = w & 63;
                if (which < 2) {
                    // RoPE: pair index i = d/2, freq = 10000^{-i/32}
                    // -ln(10000)/32 = -0.28782313662425575
                    const float fi = (float)(d >> 1);
                    const float tf = (float)t;
                    const float ang0 = tf * expf(fi * -0.28782313662425575f);
                    const float ang1 = tf * expf((fi + 1.0f) * -0.28782313662425575f);
                    const float s0 = sinf(ang0), c0 = cosf(ang0);
                    const float s1 = sinf(ang1), c1 = cosf(ang1);
                    const float e0 = v[0], od0 = v[1], e1 = v[2], od1 = v[3];
                    v[0] = e0*c0 - od0*s0;
                    v[1] = e0*s0 + od0*c0;
                    v[2] = e1*c1 - od1*s1;
                    v[3] = e1*s1 + od1*c1;
                }
                float* dst = (which == 0) ? O0 : (which == 1) ? O1 : O2;
                const size_t off = ((((size_t)b*NH + h)*T_SEQ + t) << 6) + d;
                *(float4*)&dst[off] = make_float4(v[0], v[1], v[2], v[3]);
            }
        }
    }
}

// -------------------------------------------------------------------------
// Kernel 3: flash-style fp32 attention. One block per (bh, 64-row q-tile).
// 256 threads = 16x16; thread (ty,tx) owns a 4x4 tile of S/P (rows ty*4+i,
// cols tx*4+j) and the matching 4x4 tile of O (rows ty*4+i, dims tx*4+j).
// Q and K stored transposed in LDS ([d][r]) so the hot reads are contiguous
// float4 at lane-stride 16B (2-way bank alias = free). K and V share one
// LDS buffer (load K -> S -> load V -> PV) to stay ~52KB -> 3 blocks/CU.
// -------------------------------------------------------------------------
__global__ __launch_bounds__(256, 2)
void attn_kernel(const float* __restrict__ Q, const float* __restrict__ K,
                 const float* __restrict__ V, const float* __restrict__ valid,
                 float* __restrict__ O)
{
    __shared__ float QsT[64][68];   // QsT[d][r]
    __shared__ float KVs[64][68];   // K phase: [d][r]; V phase: [k][dv]
    __shared__ float PsT[64][68];   // PsT[k][r]
    __shared__ float Ms[64];

    const int tid = threadIdx.x;
    const int tx  = tid & 15;
    const int ty  = tid >> 4;
    const int bh  = blockIdx.y;     // 0..63
    const int b   = bh >> 4;
    const int h   = bh & 15;
    const int qt  = blockIdx.x;     // 0..31

    {
        const size_t qbase = (((size_t)bh)*T_SEQ + qt*64) * HD;
#pragma unroll
        for (int p = 0; p < 4; ++p) {
            const int idx = tid + p*256;
            const int r = idx >> 4;
            const int c = (idx & 15) * 4;
            const float4 q4 = *(const float4*)&Q[qbase + r*HD + c];
            QsT[c+0][r] = q4.x; QsT[c+1][r] = q4.y; QsT[c+2][r] = q4.z; QsT[c+3][r] = q4.w;
        }
    }

    float o[4][4];
#pragma unroll
    for (int i = 0; i < 4; ++i)
#pragma unroll
        for (int j = 0; j < 4; ++j) o[i][j] = 0.0f;
    float mrow[4] = {-INFINITY, -INFINITY, -INFINITY, -INFINITY};
    float lrow[4] = {0.0f, 0.0f, 0.0f, 0.0f};

    for (int kt = 0; kt < T_SEQ/64; ++kt) {
        __syncthreads();   // prev iter's PV reads of KVs/PsT are done
        const size_t kbase = (((size_t)bh)*T_SEQ + kt*64) * HD;
#pragma unroll
        for (int p = 0; p < 4; ++p) {
            const int idx = tid + p*256;
            const int r = idx >> 4;
            const int c = (idx & 15) * 4;
            const float4 k4 = *(const float4*)&K[kbase + r*HD + c];
            KVs[c+0][r] = k4.x; KVs[c+1][r] = k4.y; KVs[c+2][r] = k4.z; KVs[c+3][r] = k4.w;
        }
        if (tid < 64) Ms[tid] = valid[b*T_SEQ + kt*64 + tid];
        __syncthreads();

        // ---- S = Q K^T (per-thread 4x4, outer-product over d) ----
        float s[4][4];
#pragma unroll
        for (int i = 0; i < 4; ++i)
#pragma unroll
            for (int j = 0; j < 4; ++j) s[i][j] = 0.0f;
#pragma unroll 4
        for (int d = 0; d < 64; ++d) {
            const float4 qv = *(const float4*)&QsT[d][ty*4];
            const float4 kv = *(const float4*)&KVs[d][tx*4];
            const float qa[4] = {qv.x, qv.y, qv.z, qv.w};
            const float ka[4] = {kv.x, kv.y, kv.z, kv.w};
#pragma unroll
            for (int i = 0; i < 4; ++i)
#pragma unroll
                for (int j = 0; j < 4; ++j)
                    s[i][j] = fmaf(qa[i], ka[j], s[i][j]);
        }

        // ---- mask + scale ----
        float mk[4];
#pragma unroll
        for (int j = 0; j < 4; ++j) mk[j] = Ms[tx*4 + j];
#pragma unroll
        for (int i = 0; i < 4; ++i)
#pragma unroll
            for (int j = 0; j < 4; ++j)
                s[i][j] = (mk[j] > 0.5f) ? s[i][j]*0.125f : -1e30f;

        // ---- online softmax (row reduce across tx = lane bits 0..3) ----
        float mnew[4], alpha[4];
#pragma unroll
        for (int i = 0; i < 4; ++i) {
            float mt = fmaxf(fmaxf(s[i][0], s[i][1]), fmaxf(s[i][2], s[i][3]));
            mt = fmaxf(mt, __shfl_xor(mt, 1));
            mt = fmaxf(mt, __shfl_xor(mt, 2));
            mt = fmaxf(mt, __shfl_xor(mt, 4));
            mt = fmaxf(mt, __shfl_xor(mt, 8));
            mnew[i]  = fmaxf(mrow[i], mt);
            alpha[i] = __expf(mrow[i] - mnew[i]);   // -inf - finite -> 0
            mrow[i]  = mnew[i];
        }
        float p[4][4];
#pragma unroll
        for (int i = 0; i < 4; ++i) {
            float lt = 0.0f;
#pragma unroll
            for (int j = 0; j < 4; ++j) { p[i][j] = __expf(s[i][j] - mnew[i]); lt += p[i][j]; }
            lt += __shfl_xor(lt, 1);
            lt += __shfl_xor(lt, 2);
            lt += __shfl_xor(lt, 4);
            lt += __shfl_xor(lt, 8);
            lrow[i] = lrow[i]*alpha[i] + lt;
#pragma unroll
            for (int j = 0; j < 4; ++j) o[i][j] *= alpha[i];
        }

        __syncthreads();   // all S-phase reads of KVs done
        // write P^T; reload KVs with V (natural [k][dv])
#pragma unroll
        for (int i = 0; i < 4; ++i)
#pragma unroll
            for (int j = 0; j < 4; ++j)
                PsT[tx*4 + j][ty*4 + i] = p[i][j];
        const size_t vbase = (((size_t)bh)*T_SEQ + kt*64) * HD;
#pragma unroll
        for (int pp = 0; pp < 4; ++pp) {
            const int idx = tid + pp*256;
            const int r = idx >> 4;
            const int c = (idx & 15) * 4;
            *(float4*)&KVs[r][c] = *(const float4*)&V[vbase + r*HD + c];
        }
        __syncthreads();

        // ---- O += P V ----
#pragma unroll 4
        for (int k = 0; k < 64; ++k) {
            const float4 pv = *(const float4*)&PsT[k][ty*4];
            const float4 vv = *(const float4*)&KVs[k][tx*4];
            const float pa[4] = {pv.x, pv.y, pv.z, pv.w};
            const float va[4] = {vv.x, vv.y, vv.z, vv.w};
#pragma unroll
            for (int i = 0; i < 4; ++i)
#pragma unroll
                for (int j = 0; j < 4; ++j)
                    o[i][j] = fmaf(pa[i], va[j], o[i][j]);
        }
    }

    // ---- normalize + store to [B,T,H*64] ----
    const size_t obase = (((size_t)b)*T_SEQ + qt*64) * DM + h*HD;
#pragma unroll
    for (int i = 0; i < 4; ++i) {
        const float inv = 1.0f / lrow[i];
        *(float4*)&O[obase + (size_t)(ty*4 + i)*DM + tx*4] =
            make_float4(o[i][0]*inv, o[i][1]*inv, o[i][2]*inv, o[i][3]*inv);
    }
}

// -------------------------------------------------------------------------
// Launch. Workspace layout (fp32):
//   Qw [64][2048][64]   8,388,608 floats (32 MB)
//   Kw                  8,388,608
//   Vw                  8,388,608
//   AO [4][2048][1024]  8,388,608  (attention output, pre-projection)
//   MSK [4][2048]       8,192
// total ~128.03 MB
// -------------------------------------------------------------------------
extern "C" void kernel_launch(void* const* d_in, const int* in_sizes, int n_in,
                              void* d_out, int out_size, void* d_ws, size_t ws_size,
                              hipStream_t stream)
{
    const float* tokens = (const float*)d_in[0];
    const int*   pad    = (const int*)d_in[1];   // bool mask as int32 per harness dtype note
    const float* Wqkv   = (const float*)d_in[2];
    const float* bqkv   = (const float*)d_in[3];
    const float* Wout   = (const float*)d_in[4];
    const float* bout   = (const float*)d_in[5];
    float* out = (float*)d_out;

    const size_t SZ = (size_t)8388608;
    float* Qw  = (float*)d_ws;
    float* Kw  = Qw + SZ;
    float* Vw  = Kw + SZ;
    float* AO  = Vw + SZ;
    float* MSK = AO + SZ;

    maskprep_kernel<<<dim3(BATCH), dim3(256), 0, stream>>>(pad, MSK);
    sgemm_kernel<1><<<dim3(24, 64), dim3(256), 0, stream>>>(
        tokens, Wqkv, bqkv, Qw, Kw, Vw, BATCH*T_SEQ, 3*DM, DM);
    attn_kernel<<<dim3(32, 64), dim3(256), 0, stream>>>(Qw, Kw, Vw, MSK, AO);
    sgemm_kernel<0><<<dim3(8, 64), dim3(256), 0, stream>>>(
        AO, Wout, bout, out, nullptr, nullptr, BATCH*T_SEQ, DM, DM);
}

// Round 2
// 1780.592 us; speedup vs baseline: 1.0309x; 1.0309x over previous
//
#include <hip/hip_runtime.h>
#include <cmath>

#define T_SEQ 2048
#define NH    16
#define HD    64
#define DM    1024
#define BATCH 4

typedef __attribute__((ext_vector_type(8))) short bf16x8;
typedef __attribute__((ext_vector_type(4))) float f32x4;
typedef unsigned short ushort_t;

// round-to-nearest-even fp32 -> bf16 bits
__device__ __forceinline__ unsigned short f2bf(float x) {
    union { float f; unsigned u; } v; v.f = x;
    unsigned r = v.u + 0x7fffu + ((v.u >> 16) & 1u);
    return (unsigned short)(r >> 16);
}
__device__ __forceinline__ float bf2f(unsigned short h) {
    union { unsigned u; float f; } v; v.u = ((unsigned)h) << 16;
    return v.f;
}

// -------------------------------------------------------------------------
// Kernel 1: mask prep. padding_mask: True(=1) = pad. If an entire row is
// padded, unmask it (safe softmax). Writes valid[b][t] in {0,1} as float.
// -------------------------------------------------------------------------
__global__ void maskprep_kernel(const int* __restrict__ pad, float* __restrict__ valid)
{
    __shared__ int sall[256];
    const int b = blockIdx.x;
    const int t = threadIdx.x;
    int allp = 1;
    for (int i = t; i < T_SEQ; i += 256) allp &= (pad[b*T_SEQ + i] != 0) ? 1 : 0;
    sall[t] = allp;
    __syncthreads();
    for (int s = 128; s > 0; s >>= 1) {
        if (t < s) sall[t] &= sall[t + s];
        __syncthreads();
    }
    const int ap = sall[0];
    for (int i = t; i < T_SEQ; i += 256) {
        const int p = (pad[b*T_SEQ + i] != 0) ? 1 : 0;
        valid[b*T_SEQ + i] = (p && !ap) ? 0.0f : 1.0f;
    }
}

// -------------------------------------------------------------------------
// Kernel 2/4: fp32 SGEMM, C[M,N] = A[M,K]@B[K,N] + bias. 128x128 tile.
// EPI=0: plain fp32 store to O0.
// EPI=1: QKV epilogue: bias + RoPE; Q scaled by 0.125; emit bf16 hi/lo:
//        Qhi/Qlo, Khi/Klo as [bh][t][64]; Vthi/Vtlo TRANSPOSED [bh][d][t].
// -------------------------------------------------------------------------
template<int EPI>
__global__ __launch_bounds__(256, 2)
void sgemm_kernel(const float* __restrict__ A, const float* __restrict__ B,
                  const float* __restrict__ bias,
                  float* __restrict__ O0,
                  ushort_t* __restrict__ Qhi, ushort_t* __restrict__ Qlo,
                  ushort_t* __restrict__ Khi, ushort_t* __restrict__ Klo,
                  ushort_t* __restrict__ Vthi, ushort_t* __restrict__ Vtlo,
                  int M, int N, int K)
{
    __shared__ float As[16][132];
    __shared__ float Bs[16][132];
    const int tid = threadIdx.x;
    const int tx  = tid & 15;
    const int ty  = tid >> 4;
    const int m0  = blockIdx.y * 128;
    const int n0  = blockIdx.x * 128;

    float acc[8][8];
#pragma unroll
    for (int i = 0; i < 8; ++i)
#pragma unroll
        for (int j = 0; j < 8; ++j) acc[i][j] = 0.0f;

    for (int kk = 0; kk < K; kk += 16) {
        __syncthreads();
#pragma unroll
        for (int p = 0; p < 2; ++p) {
            const int idx = tid + p * 256;
            const int m   = idx >> 2;
            const int kg  = (idx & 3) * 4;
            const float4 a = *(const float4*)&A[(size_t)(m0 + m) * K + kk + kg];
            As[kg+0][m] = a.x; As[kg+1][m] = a.y; As[kg+2][m] = a.z; As[kg+3][m] = a.w;
        }
#pragma unroll
        for (int p = 0; p < 2; ++p) {
            const int idx = tid + p * 256;
            const int kr  = idx >> 5;
            const int c   = (idx & 31) * 4;
            *(float4*)&Bs[kr][c] = *(const float4*)&B[(size_t)(kk + kr) * N + n0 + c];
        }
        __syncthreads();
#pragma unroll
        for (int k = 0; k < 16; ++k) {
            float a[8], b[8];
            *(float4*)&a[0] = *(const float4*)&As[k][ty*4];
            *(float4*)&a[4] = *(const float4*)&As[k][64 + ty*4];
            *(float4*)&b[0] = *(const float4*)&Bs[k][tx*4];
            *(float4*)&b[4] = *(const float4*)&Bs[k][64 + tx*4];
#pragma unroll
            for (int i = 0; i < 8; ++i)
#pragma unroll
                for (int j = 0; j < 8; ++j)
                    acc[i][j] = fmaf(a[i], b[j], acc[i][j]);
        }
    }

    // ---------------- epilogue ----------------
#pragma unroll
    for (int i = 0; i < 8; ++i) {
        const int m = m0 + ((i < 4) ? (ty*4 + i) : (64 + ty*4 + i - 4));
#pragma unroll
        for (int g = 0; g < 2; ++g) {
            const int n = n0 + g*64 + tx*4;
            float v[4];
#pragma unroll
            for (int j = 0; j < 4; ++j) v[j] = acc[i][g*4 + j] + bias[n + j];
            if (EPI == 0) {
                *(float4*)&O0[(size_t)m * N + n] = make_float4(v[0], v[1], v[2], v[3]);
            } else {
                const int b     = m >> 11;
                const int t     = m & 2047;
                const int which = n >> 10;          // 0=q 1=k 2=v
                const int w     = n & 1023;
                const int h     = w >> 6;
                const int d     = w & 63;
                const int bh    = b*NH + h;
                if (which < 2) {
                    // RoPE (d is multiple of 4 -> two even/odd pairs)
                    const float fi = (float)(d >> 1);
                    const float tf = (float)t;
                    const float ang0 = tf * expf(fi * -0.28782313662425575f);
                    const float ang1 = tf * expf((fi + 1.0f) * -0.28782313662425575f);
                    const float s0 = sinf(ang0), c0 = cosf(ang0);
                    const float s1 = sinf(ang1), c1 = cosf(ang1);
                    const float e0 = v[0], od0 = v[1], e1 = v[2], od1 = v[3];
                    v[0] = e0*c0 - od0*s0;
                    v[1] = e0*s0 + od0*c0;
                    v[2] = e1*c1 - od1*s1;
                    v[3] = e1*s1 + od1*c1;
                    if (which == 0) {
#pragma unroll
                        for (int j = 0; j < 4; ++j) v[j] *= 0.125f;  // fold 1/sqrt(hd)
                    }
                    ushort_t hi[4], lo[4];
#pragma unroll
                    for (int j = 0; j < 4; ++j) {
                        hi[j] = f2bf(v[j]);
                        lo[j] = f2bf(v[j] - bf2f(hi[j]));
                    }
                    ushort_t* dh = (which == 0) ? Qhi : Khi;
                    ushort_t* dl = (which == 0) ? Qlo : Klo;
                    const size_t off = ((((size_t)bh)*T_SEQ + t) << 6) + d;
                    *(short4*)&dh[off] = make_short4(hi[0], hi[1], hi[2], hi[3]);
                    *(short4*)&dl[off] = make_short4(lo[0], lo[1], lo[2], lo[3]);
                } else {
                    // V transposed: Vt[bh][d][t]
#pragma unroll
                    for (int j = 0; j < 4; ++j) {
                        const ushort_t hi = f2bf(v[j]);
                        const size_t off = (((size_t)bh)*HD + d + j)*T_SEQ + t;
                        Vthi[off] = hi;
                        Vtlo[off] = f2bf(v[j] - bf2f(hi));
                    }
                }
            }
        }
    }
}

// -------------------------------------------------------------------------
// Kernel 3: flash attention via split-bf16 MFMA (3-term: hi*hi+hi*lo+lo*hi).
// Block = (qt, bh), 256 threads = 4 independent waves; wave w owns q-rows
// [qt*64+w*16, +16). No __syncthreads in the K-loop: all MFMA fragments are
// loaded directly from global (L1/L2-served, 16B contiguous per lane), and
// the P C-layout -> A-layout transform goes through a WAVE-PRIVATE LDS slab.
// 16x16x32 bf16 MFMA; layouts (HW-verified per guide):
//   A[m][k]: m=lane&15, k=(lane>>4)*8+j ; B[k][n]: n=lane&15, k=(lane>>4)*8+j
//   C/D: col=lane&15, row=(lane>>4)*4+reg
// -------------------------------------------------------------------------
__global__ __launch_bounds__(256, 4)
void attn_mfma_kernel(const ushort_t* __restrict__ Qhi, const ushort_t* __restrict__ Qlo,
                      const ushort_t* __restrict__ Khi, const ushort_t* __restrict__ Klo,
                      const ushort_t* __restrict__ Vthi, const ushort_t* __restrict__ Vtlo,
                      const float* __restrict__ valid, float* __restrict__ O)
{
    __shared__ float Pb[4][16][68];   // wave-private P slab, pad 68: 2-way alias only

    const int tid  = threadIdx.x;
    const int w    = tid >> 6;
    const int ln   = tid & 63;
    const int lx   = ln & 15;
    const int quad = ln >> 4;
    const int bh   = blockIdx.y;      // 0..63
    const int b    = bh >> 4;
    const int qt   = blockIdx.x;      // 0..31
    const int qrow0 = qt*64 + w*16;

    // Q A-fragments (persistent): rows qrow0+lx, k = ks*32 + quad*8 + j
    bf16x8 qh[2], ql[2];
    {
        const size_t qoff = (((size_t)bh)*T_SEQ + qrow0 + lx)*HD + quad*8;
        qh[0] = *(const bf16x8*)&Qhi[qoff];
        qh[1] = *(const bf16x8*)&Qhi[qoff + 32];
        ql[0] = *(const bf16x8*)&Qlo[qoff];
        ql[1] = *(const bf16x8*)&Qlo[qoff + 32];
    }

    f32x4 o[4];
#pragma unroll
    for (int nt = 0; nt < 4; ++nt) o[nt] = (f32x4){0.f, 0.f, 0.f, 0.f};
    float mrow[4] = {-INFINITY, -INFINITY, -INFINITY, -INFINITY};
    float lrow[4] = {0.f, 0.f, 0.f, 0.f};

    const size_t krow_base  = ((size_t)bh)*T_SEQ;        // K rows
    const size_t vt_base    = ((size_t)bh)*HD;           // Vt rows (d)
    const float* vrow = &valid[(size_t)b*T_SEQ];

    for (int kt = 0; kt < T_SEQ/64; ++kt) {
        // ---- S = (Q/8) K^T via 3-term split MFMA; 4 ntiles of 16 k-cols ----
        f32x4 s[4];
#pragma unroll
        for (int nt = 0; nt < 4; ++nt) {
            s[nt] = (f32x4){0.f, 0.f, 0.f, 0.f};
            const size_t ko = (krow_base + kt*64 + nt*16 + lx)*HD + quad*8;
            const bf16x8 kh0 = *(const bf16x8*)&Khi[ko];
            const bf16x8 kh1 = *(const bf16x8*)&Khi[ko + 32];
            const bf16x8 kl0 = *(const bf16x8*)&Klo[ko];
            const bf16x8 kl1 = *(const bf16x8*)&Klo[ko + 32];
            s[nt] = __builtin_amdgcn_mfma_f32_16x16x32_bf16(qh[0], kh0, s[nt], 0, 0, 0);
            s[nt] = __builtin_amdgcn_mfma_f32_16x16x32_bf16(qh[1], kh1, s[nt], 0, 0, 0);
            s[nt] = __builtin_amdgcn_mfma_f32_16x16x32_bf16(qh[0], kl0, s[nt], 0, 0, 0);
            s[nt] = __builtin_amdgcn_mfma_f32_16x16x32_bf16(qh[1], kl1, s[nt], 0, 0, 0);
            s[nt] = __builtin_amdgcn_mfma_f32_16x16x32_bf16(ql[0], kh0, s[nt], 0, 0, 0);
            s[nt] = __builtin_amdgcn_mfma_f32_16x16x32_bf16(ql[1], kh1, s[nt], 0, 0, 0);
        }

        // ---- mask ----
        float mk[4];
#pragma unroll
        for (int nt = 0; nt < 4; ++nt) mk[nt] = vrow[kt*64 + nt*16 + lx];
#pragma unroll
        for (int nt = 0; nt < 4; ++nt) {
            const bool ok = mk[nt] > 0.5f;
#pragma unroll
            for (int r = 0; r < 4; ++r) s[nt][r] = ok ? s[nt][r] : -1e30f;
        }

        // ---- online softmax; lane's reg r is row quad*4+r, col lane&15 per nt ----
        float alpha[4], mnew[4];
#pragma unroll
        for (int r = 0; r < 4; ++r) {
            float mt = fmaxf(fmaxf(s[0][r], s[1][r]), fmaxf(s[2][r], s[3][r]));
            mt = fmaxf(mt, __shfl_xor(mt, 1));
            mt = fmaxf(mt, __shfl_xor(mt, 2));
            mt = fmaxf(mt, __shfl_xor(mt, 4));
            mt = fmaxf(mt, __shfl_xor(mt, 8));
            mnew[r]  = fmaxf(mrow[r], mt);
            alpha[r] = __expf(mrow[r] - mnew[r]);
            mrow[r]  = mnew[r];
        }
        float p[4][4];   // [nt][r]
#pragma unroll
        for (int r = 0; r < 4; ++r) {
            float lt = 0.f;
#pragma unroll
            for (int nt = 0; nt < 4; ++nt) { p[nt][r] = __expf(s[nt][r] - mnew[r]); lt += p[nt][r]; }
            lt += __shfl_xor(lt, 1);
            lt += __shfl_xor(lt, 2);
            lt += __shfl_xor(lt, 4);
            lt += __shfl_xor(lt, 8);
            lrow[r] = lrow[r]*alpha[r] + lt;
#pragma unroll
            for (int nt = 0; nt < 4; ++nt) o[nt][r] *= alpha[r];
        }

        // ---- P: C-layout -> A-layout via wave-private LDS (no barrier) ----
#pragma unroll
        for (int nt = 0; nt < 4; ++nt)
#pragma unroll
            for (int r = 0; r < 4; ++r)
                Pb[w][quad*4 + r][nt*16 + lx] = p[nt][r];

        bf16x8 ph[2], pl[2];
#pragma unroll
        for (int ks = 0; ks < 2; ++ks) {
            float pv[8];
            *(f32x4*)&pv[0] = *(const f32x4*)&Pb[w][lx][ks*32 + quad*8];
            *(f32x4*)&pv[4] = *(const f32x4*)&Pb[w][lx][ks*32 + quad*8 + 4];
            unsigned short hbits[8], lbits[8];
#pragma unroll
            for (int j = 0; j < 8; ++j) {
                hbits[j] = f2bf(pv[j]);
                lbits[j] = f2bf(pv[j] - bf2f(hbits[j]));
            }
#pragma unroll
            for (int j = 0; j < 8; ++j) { ph[ks][j] = (short)hbits[j]; pl[ks][j] = (short)lbits[j]; }
        }

        // ---- O += P V  (B-frags from transposed V, 16B contiguous) ----
#pragma unroll
        for (int nt = 0; nt < 4; ++nt) {
            const size_t vo = (vt_base + nt*16 + lx)*T_SEQ + kt*64 + quad*8;
            const bf16x8 vh0 = *(const bf16x8*)&Vthi[vo];
            const bf16x8 vh1 = *(const bf16x8*)&Vthi[vo + 32];
            const bf16x8 vl0 = *(const bf16x8*)&Vtlo[vo];
            const bf16x8 vl1 = *(const bf16x8*)&Vtlo[vo + 32];
            o[nt] = __builtin_amdgcn_mfma_f32_16x16x32_bf16(ph[0], vh0, o[nt], 0, 0, 0);
            o[nt] = __builtin_amdgcn_mfma_f32_16x16x32_bf16(ph[1], vh1, o[nt], 0, 0, 0);
            o[nt] = __builtin_amdgcn_mfma_f32_16x16x32_bf16(ph[0], vl0, o[nt], 0, 0, 0);
            o[nt] = __builtin_amdgcn_mfma_f32_16x16x32_bf16(ph[1], vl1, o[nt], 0, 0, 0);
            o[nt] = __builtin_amdgcn_mfma_f32_16x16x32_bf16(pl[0], vh0, o[nt], 0, 0, 0);
            o[nt] = __builtin_amdgcn_mfma_f32_16x16x32_bf16(pl[1], vh1, o[nt], 0, 0, 0);
        }
    }

    // ---- normalize + store to AO[b][t][h*64+dv] (fp32) ----
    const int h = bh & 15;
    float inv[4];
#pragma unroll
    for (int r = 0; r < 4; ++r) inv[r] = 1.0f / lrow[r];
#pragma unroll
    for (int nt = 0; nt < 4; ++nt)
#pragma unroll
        for (int r = 0; r < 4; ++r) {
            const int t = qrow0 + quad*4 + r;
            O[(((size_t)b)*T_SEQ + t)*DM + h*HD + nt*16 + lx] = o[nt][r] * inv[r];
        }
}

// -------------------------------------------------------------------------
// Workspace layout:
//   AO   [4][2048][1024] f32          32 MB
//   MSK  [4][2048]       f32          32 KB
//   Qhi,Qlo,Khi,Klo [64][2048][64] bf16 bits   4 x 16 MB
//   Vthi,Vtlo       [64][64][2048] bf16 bits   2 x 16 MB
// total ~128.03 MB
// -------------------------------------------------------------------------
extern "C" void kernel_launch(void* const* d_in, const int* in_sizes, int n_in,
                              void* d_out, int out_size, void* d_ws, size_t ws_size,
                              hipStream_t stream)
{
    const float* tokens = (const float*)d_in[0];
    const int*   pad    = (const int*)d_in[1];
    const float* Wqkv   = (const float*)d_in[2];
    const float* bqkv   = (const float*)d_in[3];
    const float* Wout   = (const float*)d_in[4];
    const float* bout   = (const float*)d_in[5];
    float* out = (float*)d_out;

    const size_t SZ = (size_t)8388608;           // elements per [64][2048][64] array
    float* AO  = (float*)d_ws;
    float* MSK = AO + SZ;
    ushort_t* U = (ushort_t*)(MSK + 8192);
    ushort_t* Qhi  = U;
    ushort_t* Qlo  = U + SZ;
    ushort_t* Khi  = U + 2*SZ;
    ushort_t* Klo  = U + 3*SZ;
    ushort_t* Vthi = U + 4*SZ;
    ushort_t* Vtlo = U + 5*SZ;

    maskprep_kernel<<<dim3(BATCH), dim3(256), 0, stream>>>(pad, MSK);
    sgemm_kernel<1><<<dim3(24, 64), dim3(256), 0, stream>>>(
        tokens, Wqkv, bqkv, nullptr, Qhi, Qlo, Khi, Klo, Vthi, Vtlo,
        BATCH*T_SEQ, 3*DM, DM);
    attn_mfma_kernel<<<dim3(32, 64), dim3(256), 0, stream>>>(
        Qhi, Qlo, Khi, Klo, Vthi, Vtlo, MSK, AO);
    sgemm_kernel<0><<<dim3(8, 64), dim3(256), 0, stream>>>(
        AO, Wout, bout, out, nullptr, nullptr, nullptr, nullptr, nullptr, nullptr,
        BATCH*T_SEQ, DM, DM);
}